// Round 6
// baseline (1085.477 us; speedup 1.0000x reference)
//
#include <hip/hip_runtime.h>
#include <hip/hip_bf16.h>
#include <hip/hip_cooperative_groups.h>
#include <math.h>

#define NCH 32

namespace cg = cooperative_groups;

typedef unsigned short ushort_t;
typedef unsigned int uint_t;
typedef unsigned char uchar_t;

static __device__ __forceinline__ float bf2f(ushort_t b) {
    return __uint_as_float(((uint_t)b) << 16);
}
static __device__ __forceinline__ ushort_t f2bf(float f) {
    __hip_bfloat16 h = __float2bfloat16(f);
    return *reinterpret_cast<ushort_t*>(&h);
}

using f32x2 = __attribute__((ext_vector_type(2))) float;

// --- packed bf16 global atomic with compile-safe fallback ------------------
template <typename T>
__device__ __forceinline__ auto pkAddImpl(T* p, T v, int)
    -> decltype(unsafeAtomicAdd(p, v), void()) {
    unsafeAtomicAdd(p, v);
}
template <typename T>
__device__ void pkAddImpl(T* p, T v, long) {
    uint_t* q = reinterpret_cast<uint_t*>(p);
    uint_t vv = *reinterpret_cast<uint_t*>(&v);
    uint_t cur = *q;
    while (true) {
        float lo = bf2f((ushort_t)(cur & 0xFFFF)) + bf2f((ushort_t)(vv & 0xFFFF));
        float hi = bf2f((ushort_t)(cur >> 16)) + bf2f((ushort_t)(vv >> 16));
        uint_t nw = (uint_t)f2bf(lo) | ((uint_t)f2bf(hi) << 16);
        uint_t prev = atomicCAS(q, cur, nw);
        if (prev == cur) break;
        cur = prev;
    }
}
static __device__ __forceinline__ void pkAdd(__hip_bfloat162* p, float z0, float z1) {
    __hip_bfloat162 v;
    v.x = __float2bfloat16(z0);
    v.y = __float2bfloat16(z1);
    pkAddImpl(p, v, 0);
}

// ===========================================================================
// Round-19: fused cooperative pipeline of the PROVEN r13 kernels.
//   r18 post-mortem: bin-consumer apply stuck at 272us with ALL pipes <8%
//   busy across two different configs (occ 37->70%, conflicts 396K->0,
//   dur identical) — unmodelable serialization; abandoned per discipline.
//   Facts: r13 edge-parallel kernels are proven fast (apply_pk 87us @3TB/s,
//   stats8 86us, uv3 10us, cvt 13us; sum ~200us) but r13 TOTAL was 309us
//   -> ~110us was inter-dispatch overhead over 6 launches.
//   Fix: ONE cooperative kernel: uv -> sync -> stats -> sync -> finalize
//   -> sync -> apply(pk) -> sync -> cvt. threadfence+grid.sync for
//   cross-XCD visibility. memset folded into phase 0. Occupancy-sized
//   grid; verbatim r13 sequence as fallback if coop can't launch.
// ===========================================================================

__global__ __launch_bounds__(256) void k_fused(
    const float* __restrict__ x, const int* __restrict__ srci,
    const int* __restrict__ tgti, const float* __restrict__ W,
    const float* __restrict__ gamma, const float* __restrict__ beta,
    ushort_t* __restrict__ uh, ushort_t* __restrict__ vh,
    uchar_t* __restrict__ uq, uchar_t* __restrict__ vq,
    __hip_bfloat162* __restrict__ outh, float* __restrict__ partials,
    float* __restrict__ ab, float* __restrict__ out, int N, int E)
{
    cg::grid_group grid = cg::this_grid();

    __shared__ float At[NCH * NCH];   // phase 0
    __shared__ float Bt[NCH * NCH];
    __shared__ float sL[16][32];      // phase 1
    __shared__ float qL[16][32];
    __shared__ float acc[4][64];      // phase 2

    // ---------------- phase 0: u,v (bf16+fp8) + zero outh ------------------
    for (int i = threadIdx.x; i < NCH * NCH; i += 256) {
        const int k = i >> 5, c = i & 31;
        const float w1 = W[c * 64 + k];
        const float w2 = W[c * 64 + 32 + k];
        At[i] = w1 - w2;
        Bt[i] = w2;
    }
    __syncthreads();
    {
        const int sub = threadIdx.x >> 5;
        const int c = threadIdx.x & 31;
        for (int n0 = blockIdx.x * 8; n0 < N; n0 += gridDim.x * 8) {
            const int n = n0 + sub;
            if (n < N) {
                const float xc = x[(size_t)n * NCH + c];
                float su = 0.f, sv = 0.f;
#pragma unroll
                for (int k = 0; k < NCH; ++k) {
                    const float xk = __shfl(xc, k, 32);
                    su = fmaf(At[k * 32 + c], xk, su);
                    sv = fmaf(Bt[k * 32 + c], xk, sv);
                }
                uh[(size_t)n * NCH + c] = f2bf(su);
                vh[(size_t)n * NCH + c] = f2bf(sv);
                uq[(size_t)n * NCH + c] =
                    (uchar_t)(__builtin_amdgcn_cvt_pk_fp8_f32(su, su, 0, false) & 0xFF);
                vq[(size_t)n * NCH + c] =
                    (uchar_t)(__builtin_amdgcn_cvt_pk_fp8_f32(sv, sv, 0, false) & 0xFF);
            }
        }
        uint_t* o32 = (uint_t*)outh;
        const int M = N * 16;
        for (int i = blockIdx.x * 256 + threadIdx.x; i < M; i += gridDim.x * 256)
            o32[i] = 0u;
    }
    __threadfence();
    grid.sync();

    // ---------------- phase 1: BN stats over fp8 u,v -----------------------
    {
        const ushort_t* __restrict__ uq16 = (const ushort_t*)uq;
        const ushort_t* __restrict__ vq16 = (const ushort_t*)vq;
        const int l  = threadIdx.x & 15;    // channel pair (2l, 2l+1)
        const int g  = (blockIdx.x * 256 + threadIdx.x) >> 4;
        const int nG = (gridDim.x * 256) >> 4;

        float s0 = 0.f, s1 = 0.f, q0 = 0.f, q1 = 0.f;
        int e = g;
        for (; e + 3 * nG < E; e += 4 * nG) {
            const int ea = e, eb = e + nG, ec = e + 2 * nG, ed = e + 3 * nG;
            const int sa = srci[ea], sb = srci[eb], sc = srci[ec], sd = srci[ed];
            const int ta = tgti[ea], tb = tgti[eb], tc = tgti[ec], td = tgti[ed];
            const ushort_t ua = uq16[(size_t)sa * 16 + l];
            const ushort_t ub = uq16[(size_t)sb * 16 + l];
            const ushort_t uc = uq16[(size_t)sc * 16 + l];
            const ushort_t ud = uq16[(size_t)sd * 16 + l];
            const ushort_t va = vq16[(size_t)ta * 16 + l];
            const ushort_t vb = vq16[(size_t)tb * 16 + l];
            const ushort_t vc = vq16[(size_t)tc * 16 + l];
            const ushort_t vd = vq16[(size_t)td * 16 + l];
#pragma unroll
            for (int k = 0; k < 4; ++k) {
                const ushort_t uu = (k == 0) ? ua : (k == 1) ? ub : (k == 2) ? uc : ud;
                const ushort_t vvv = (k == 0) ? va : (k == 1) ? vb : (k == 2) ? vc : vd;
                const f32x2 uf = __builtin_amdgcn_cvt_pk_f32_fp8((int)uu, false);
                const f32x2 vf = __builtin_amdgcn_cvt_pk_f32_fp8((int)vvv, false);
                const float y0 = uf.x + vf.x;
                const float y1 = uf.y + vf.y;
                s0 += y0; q0 = fmaf(y0, y0, q0);
                s1 += y1; q1 = fmaf(y1, y1, q1);
            }
        }
        for (; e < E; e += nG) {
            const int s = srci[e], t = tgti[e];
            const f32x2 uf = __builtin_amdgcn_cvt_pk_f32_fp8((int)uq16[(size_t)s * 16 + l], false);
            const f32x2 vf = __builtin_amdgcn_cvt_pk_f32_fp8((int)vq16[(size_t)t * 16 + l], false);
            const float y0 = uf.x + vf.x;
            const float y1 = uf.y + vf.y;
            s0 += y0; q0 = fmaf(y0, y0, q0);
            s1 += y1; q1 = fmaf(y1, y1, q1);
        }

        const int grp = threadIdx.x >> 4;
        sL[grp][2 * l + 0] = s0;
        sL[grp][2 * l + 1] = s1;
        qL[grp][2 * l + 0] = q0;
        qL[grp][2 * l + 1] = q1;
        __syncthreads();
        if (threadIdx.x < 32) {
            float a = 0.f;
#pragma unroll
            for (int r = 0; r < 16; ++r) a += sL[r][threadIdx.x];
            partials[(size_t)blockIdx.x * 64 + threadIdx.x] = a;
        } else if (threadIdx.x < 64) {
            const int cc = threadIdx.x - 32;
            float a = 0.f;
#pragma unroll
            for (int r = 0; r < 16; ++r) a += qL[r][cc];
            partials[(size_t)blockIdx.x * 64 + 32 + cc] = a;
        }
    }
    __threadfence();
    grid.sync();

    // ---------------- phase 2: finalize -> ab (block 0 only) ---------------
    if (blockIdx.x == 0) {
        const int vtx = threadIdx.x & 63, chunk = threadIdx.x >> 6;
        float s = 0.f;
        for (int r = chunk; r < (int)gridDim.x; r += 4)
            s += partials[(size_t)r * 64 + vtx];
        acc[chunk][vtx] = s;
        __syncthreads();
        if (threadIdx.x < 64)
            acc[0][vtx] = acc[0][vtx] + acc[1][vtx] + acc[2][vtx] + acc[3][vtx];
        __syncthreads();
        if (threadIdx.x < 32) {
            const int c = threadIdx.x;
            const float invE = 1.0f / (float)E;
            float mean = acc[0][c] * invE;
            float var  = acc[0][32 + c] * invE - mean * mean;
            float rstd = rsqrtf(var + 1e-5f);
            float a = gamma[c] * rstd;
            ab[c] = a; ab[32 + c] = beta[c] - mean * a;
        }
    }
    __threadfence();
    grid.sync();

    // ---------------- phase 3: apply with pk-bf16 atomics ------------------
    {
        const uint_t* __restrict__ uh32 = (const uint_t*)uh;
        const uint_t* __restrict__ vh32 = (const uint_t*)vh;
        const int l  = threadIdx.x & 15;
        const float a0 = ab[2 * l + 0], a1 = ab[2 * l + 1];
        const float b0 = ab[32 + 2 * l + 0], b1 = ab[32 + 2 * l + 1];
        const int g  = (blockIdx.x * 256 + threadIdx.x) >> 4;
        const int nG = (gridDim.x * 256) >> 4;

        int e = g;
        for (; e + 3 * nG < E; e += 4 * nG) {
            const int ea = e, eb = e + nG, ec = e + 2 * nG, ed = e + 3 * nG;
            const int sa = srci[ea], sb = srci[eb], sc = srci[ec], sd = srci[ed];
            const int ta = tgti[ea], tb = tgti[eb], tc = tgti[ec], td = tgti[ed];
            const uint_t Ua = uh32[(size_t)sa * 16 + l];
            const uint_t Ub = uh32[(size_t)sb * 16 + l];
            const uint_t Uc = uh32[(size_t)sc * 16 + l];
            const uint_t Ud = uh32[(size_t)sd * 16 + l];
            const uint_t Va = vh32[(size_t)ta * 16 + l];
            const uint_t Vb = vh32[(size_t)tb * 16 + l];
            const uint_t Vc = vh32[(size_t)tc * 16 + l];
            const uint_t Vd = vh32[(size_t)td * 16 + l];
            const int ss[4] = {sa, sb, sc, sd};
            const uint_t UU[4] = {Ua, Ub, Uc, Ud};
            const uint_t VV[4] = {Va, Vb, Vc, Vd};
#pragma unroll
            for (int k = 0; k < 4; ++k) {
                const float y0 = bf2f((ushort_t)(UU[k] & 0xFFFF)) + bf2f((ushort_t)(VV[k] & 0xFFFF));
                const float y1 = bf2f((ushort_t)(UU[k] >> 16))    + bf2f((ushort_t)(VV[k] >> 16));
                float z0 = fmaf(a0, y0, b0);
                float z1 = fmaf(a1, y1, b1);
                z0 = (z0 > 0.f) ? z0 : (__expf(z0) - 1.0f);
                z1 = (z1 > 0.f) ? z1 : (__expf(z1) - 1.0f);
                pkAdd(&outh[(size_t)ss[k] * 16 + l], z0, z1);
            }
        }
        for (; e < E; e += nG) {
            const int s = srci[e], t = tgti[e];
            const uint_t U = uh32[(size_t)s * 16 + l];
            const uint_t V = vh32[(size_t)t * 16 + l];
            const float y0 = bf2f((ushort_t)(U & 0xFFFF)) + bf2f((ushort_t)(V & 0xFFFF));
            const float y1 = bf2f((ushort_t)(U >> 16))    + bf2f((ushort_t)(V >> 16));
            float z0 = fmaf(a0, y0, b0);
            float z1 = fmaf(a1, y1, b1);
            z0 = (z0 > 0.f) ? z0 : (__expf(z0) - 1.0f);
            z1 = (z1 > 0.f) ? z1 : (__expf(z1) - 1.0f);
            pkAdd(&outh[(size_t)s * 16 + l], z0, z1);
        }
    }
    __threadfence();
    grid.sync();

    // ---------------- phase 4: cvt bf16 accumulator -> fp32 out ------------
    {
        const uint_t* o32 = (const uint_t*)outh;
        const int M = N * 16;
        for (int i = blockIdx.x * 256 + threadIdx.x; i < M; i += gridDim.x * 256) {
            const uint_t w = o32[i];
            float2 f;
            f.x = bf2f((ushort_t)(w & 0xFFFF));
            f.y = bf2f((ushort_t)(w >> 16));
            ((float2*)out)[i] = f;
        }
    }
}

// ===========================================================================
// FALLBACK A: verbatim r13 sequence (proven 309us) if coop launch unavailable
// ===========================================================================
__global__ __launch_bounds__(256) void k_uv3(
    const float* __restrict__ x, const float* __restrict__ W,
    ushort_t* __restrict__ uh, ushort_t* __restrict__ vh,
    uchar_t* __restrict__ uq, uchar_t* __restrict__ vq, int N)
{
    __shared__ float At[NCH * NCH];
    __shared__ float Bt[NCH * NCH];
    for (int i = threadIdx.x; i < NCH * NCH; i += 256) {
        const int k = i >> 5, c = i & 31;
        const float w1 = W[c * 64 + k];
        const float w2 = W[c * 64 + 32 + k];
        At[i] = w1 - w2;
        Bt[i] = w2;
    }
    __syncthreads();
    const int n = blockIdx.x * 8 + (threadIdx.x >> 5);
    const int c = threadIdx.x & 31;
    if (n >= N) return;
    const float xc = x[(size_t)n * NCH + c];
    float su = 0.f, sv = 0.f;
#pragma unroll
    for (int k = 0; k < NCH; ++k) {
        const float xk = __shfl(xc, k, 32);
        su = fmaf(At[k * 32 + c], xk, su);
        sv = fmaf(Bt[k * 32 + c], xk, sv);
    }
    uh[(size_t)n * NCH + c] = f2bf(su);
    vh[(size_t)n * NCH + c] = f2bf(sv);
    uq[(size_t)n * NCH + c] =
        (uchar_t)(__builtin_amdgcn_cvt_pk_fp8_f32(su, su, 0, false) & 0xFF);
    vq[(size_t)n * NCH + c] =
        (uchar_t)(__builtin_amdgcn_cvt_pk_fp8_f32(sv, sv, 0, false) & 0xFF);
}

__global__ __launch_bounds__(256) void k_stats8(
    const uchar_t* __restrict__ uq, const uchar_t* __restrict__ vq,
    const int* __restrict__ srci, const int* __restrict__ tgti,
    float* __restrict__ partials, int E)
{
    const ushort_t* __restrict__ uq16 = (const ushort_t*)uq;
    const ushort_t* __restrict__ vq16 = (const ushort_t*)vq;
    const int l  = threadIdx.x & 15;
    const int g  = (blockIdx.x * 256 + threadIdx.x) >> 4;
    const int nG = (gridDim.x * 256) >> 4;

    float s0 = 0.f, s1 = 0.f, q0 = 0.f, q1 = 0.f;
    int e = g;
    for (; e + 3 * nG < E; e += 4 * nG) {
        const int ea = e, eb = e + nG, ec = e + 2 * nG, ed = e + 3 * nG;
        const int sa = srci[ea], sb = srci[eb], sc = srci[ec], sd = srci[ed];
        const int ta = tgti[ea], tb = tgti[eb], tc = tgti[ec], td = tgti[ed];
        const ushort_t ua = uq16[(size_t)sa * 16 + l];
        const ushort_t ub = uq16[(size_t)sb * 16 + l];
        const ushort_t uc = uq16[(size_t)sc * 16 + l];
        const ushort_t ud = uq16[(size_t)sd * 16 + l];
        const ushort_t va = vq16[(size_t)ta * 16 + l];
        const ushort_t vb = vq16[(size_t)tb * 16 + l];
        const ushort_t vc = vq16[(size_t)tc * 16 + l];
        const ushort_t vd = vq16[(size_t)td * 16 + l];
#pragma unroll
        for (int k = 0; k < 4; ++k) {
            const ushort_t uu = (k == 0) ? ua : (k == 1) ? ub : (k == 2) ? uc : ud;
            const ushort_t vv = (k == 0) ? va : (k == 1) ? vb : (k == 2) ? vc : vd;
            const f32x2 uf = __builtin_amdgcn_cvt_pk_f32_fp8((int)uu, false);
            const f32x2 vf = __builtin_amdgcn_cvt_pk_f32_fp8((int)vv, false);
            const float y0 = uf.x + vf.x;
            const float y1 = uf.y + vf.y;
            s0 += y0; q0 = fmaf(y0, y0, q0);
            s1 += y1; q1 = fmaf(y1, y1, q1);
        }
    }
    for (; e < E; e += nG) {
        const int s = srci[e], t = tgti[e];
        const f32x2 uf = __builtin_amdgcn_cvt_pk_f32_fp8((int)uq16[(size_t)s * 16 + l], false);
        const f32x2 vf = __builtin_amdgcn_cvt_pk_f32_fp8((int)vq16[(size_t)t * 16 + l], false);
        const float y0 = uf.x + vf.x;
        const float y1 = uf.y + vf.y;
        s0 += y0; q0 = fmaf(y0, y0, q0);
        s1 += y1; q1 = fmaf(y1, y1, q1);
    }

    __shared__ float sL[16][32];
    __shared__ float qL[16][32];
    const int grp = threadIdx.x >> 4;
    sL[grp][2 * l + 0] = s0;
    sL[grp][2 * l + 1] = s1;
    qL[grp][2 * l + 0] = q0;
    qL[grp][2 * l + 1] = q1;
    __syncthreads();
    if (threadIdx.x < 32) {
        float a = 0.f;
#pragma unroll
        for (int r = 0; r < 16; ++r) a += sL[r][threadIdx.x];
        partials[(size_t)blockIdx.x * 64 + threadIdx.x] = a;
    } else if (threadIdx.x < 64) {
        const int cc = threadIdx.x - 32;
        float a = 0.f;
#pragma unroll
        for (int r = 0; r < 16; ++r) a += qL[r][cc];
        partials[(size_t)blockIdx.x * 64 + 32 + cc] = a;
    }
}

__global__ __launch_bounds__(256) void k_finalize(
    const float* __restrict__ partials, int nblocks,
    const float* __restrict__ gamma, const float* __restrict__ beta,
    float* __restrict__ ab, float invE)
{
    __shared__ float acc[4][64];
    const int vtx = threadIdx.x & 63, chunk = threadIdx.x >> 6;
    float s = 0.f;
    for (int r = chunk; r < nblocks; r += 4) s += partials[(size_t)r * 64 + vtx];
    acc[chunk][vtx] = s;
    __syncthreads();
    if (threadIdx.x < 64) acc[0][vtx] = acc[0][vtx] + acc[1][vtx] + acc[2][vtx] + acc[3][vtx];
    __syncthreads();
    if (threadIdx.x < 32) {
        const int c = threadIdx.x;
        float mean = acc[0][c] * invE;
        float var  = acc[0][32 + c] * invE - mean * mean;
        float rstd = rsqrtf(var + 1e-5f);
        float a = gamma[c] * rstd;
        ab[c] = a; ab[32 + c] = beta[c] - mean * a;
    }
}

__global__ __launch_bounds__(256) void k_apply_pk(
    const ushort_t* __restrict__ uh, const ushort_t* __restrict__ vh,
    const int* __restrict__ srci, const int* __restrict__ tgti,
    const float* __restrict__ ab,
    __hip_bfloat162* __restrict__ outh, int E)
{
    const uint_t* __restrict__ uh32 = (const uint_t*)uh;
    const uint_t* __restrict__ vh32 = (const uint_t*)vh;
    const int l  = threadIdx.x & 15;
    const float a0 = ab[2 * l + 0], a1 = ab[2 * l + 1];
    const float b0 = ab[32 + 2 * l + 0], b1 = ab[32 + 2 * l + 1];
    const int g  = (blockIdx.x * 256 + threadIdx.x) >> 4;
    const int nG = (gridDim.x * 256) >> 4;

    int e = g;
    for (; e + 3 * nG < E; e += 4 * nG) {
        const int ea = e, eb = e + nG, ec = e + 2 * nG, ed = e + 3 * nG;
        const int sa = srci[ea], sb = srci[eb], sc = srci[ec], sd = srci[ed];
        const int ta = tgti[ea], tb = tgti[eb], tc = tgti[ec], td = tgti[ed];
        const uint_t Ua = uh32[(size_t)sa * 16 + l];
        const uint_t Ub = uh32[(size_t)sb * 16 + l];
        const uint_t Uc = uh32[(size_t)sc * 16 + l];
        const uint_t Ud = uh32[(size_t)sd * 16 + l];
        const uint_t Va = vh32[(size_t)ta * 16 + l];
        const uint_t Vb = vh32[(size_t)tb * 16 + l];
        const uint_t Vc = vh32[(size_t)tc * 16 + l];
        const uint_t Vd = vh32[(size_t)td * 16 + l];
        const int ss[4] = {sa, sb, sc, sd};
        const uint_t UU[4] = {Ua, Ub, Uc, Ud};
        const uint_t VV[4] = {Va, Vb, Vc, Vd};
#pragma unroll
        for (int k = 0; k < 4; ++k) {
            const float y0 = bf2f((ushort_t)(UU[k] & 0xFFFF)) + bf2f((ushort_t)(VV[k] & 0xFFFF));
            const float y1 = bf2f((ushort_t)(UU[k] >> 16))    + bf2f((ushort_t)(VV[k] >> 16));
            float z0 = fmaf(a0, y0, b0);
            float z1 = fmaf(a1, y1, b1);
            z0 = (z0 > 0.f) ? z0 : (__expf(z0) - 1.0f);
            z1 = (z1 > 0.f) ? z1 : (__expf(z1) - 1.0f);
            pkAdd(&outh[(size_t)ss[k] * 16 + l], z0, z1);
        }
    }
    for (; e < E; e += nG) {
        const int s = srci[e], t = tgti[e];
        const uint_t U = uh32[(size_t)s * 16 + l];
        const uint_t V = vh32[(size_t)t * 16 + l];
        const float y0 = bf2f((ushort_t)(U & 0xFFFF)) + bf2f((ushort_t)(V & 0xFFFF));
        const float y1 = bf2f((ushort_t)(U >> 16))    + bf2f((ushort_t)(V >> 16));
        float z0 = fmaf(a0, y0, b0);
        float z1 = fmaf(a1, y1, b1);
        z0 = (z0 > 0.f) ? z0 : (__expf(z0) - 1.0f);
        z1 = (z1 > 0.f) ? z1 : (__expf(z1) - 1.0f);
        pkAdd(&outh[(size_t)s * 16 + l], z0, z1);
    }
}

__global__ __launch_bounds__(256) void k_cvt(
    const uint_t* __restrict__ outh32, float* __restrict__ out, int M)
{
    const int i = blockIdx.x * 256 + threadIdx.x;
    if (i >= M) return;
    const uint_t w = outh32[i];
    float2 f;
    f.x = bf2f((ushort_t)(w & 0xFFFF));
    f.y = bf2f((ushort_t)(w >> 16));
    ((float2*)out)[i] = f;
}

// ===========================================================================
// FALLBACK B (round-1 proven path) — only if ws too small
// ===========================================================================
__global__ __launch_bounds__(256) void k_stats_hist(
    const float* __restrict__ x,
    const int* __restrict__ srci, const int* __restrict__ tgti,
    const float* __restrict__ W,
    float* __restrict__ partials, int E)
{
    float sum[NCH], ssq[NCH];
#pragma unroll
    for (int c = 0; c < NCH; ++c) { sum[c] = 0.f; ssq[c] = 0.f; }
    const int stride = gridDim.x * blockDim.x;
    for (int e = blockIdx.x * blockDim.x + threadIdx.x; e < E; e += stride) {
        const int s = srci[e], t = tgti[e];
        const float4* ps = (const float4*)(x + (size_t)s * NCH);
        const float4* pt = (const float4*)(x + (size_t)t * NCH);
        float xs[NCH], dx[NCH];
#pragma unroll
        for (int i = 0; i < 8; ++i) {
            float4 a = ps[i], bb = pt[i];
            xs[4*i+0] = a.x; xs[4*i+1] = a.y; xs[4*i+2] = a.z; xs[4*i+3] = a.w;
            dx[4*i+0] = bb.x - a.x; dx[4*i+1] = bb.y - a.y;
            dx[4*i+2] = bb.z - a.z; dx[4*i+3] = bb.w - a.w;
        }
#pragma unroll
        for (int c = 0; c < NCH; ++c) {
            const float* wr = W + c * 64;
            float y = 0.f;
#pragma unroll
            for (int k = 0; k < NCH; ++k) y = fmaf(wr[k], xs[k], y);
#pragma unroll
            for (int k = 0; k < NCH; ++k) y = fmaf(wr[32 + k], dx[k], y);
            sum[c] += y;
            ssq[c] = fmaf(y, y, ssq[c]);
        }
    }
#pragma unroll
    for (int c = 0; c < NCH; ++c) {
#pragma unroll
        for (int off = 32; off > 0; off >>= 1) {
            sum[c] += __shfl_down(sum[c], off);
            ssq[c] += __shfl_down(ssq[c], off);
        }
    }
    __shared__ float red[4][64];
    const int lane = threadIdx.x & 63, wave = threadIdx.x >> 6;
    if (lane == 0) {
#pragma unroll
        for (int c = 0; c < NCH; ++c) { red[wave][c] = sum[c]; red[wave][NCH+c] = ssq[c]; }
    }
    __syncthreads();
    if (threadIdx.x < 64)
        partials[(size_t)blockIdx.x * 64 + threadIdx.x] =
            red[0][threadIdx.x] + red[1][threadIdx.x] + red[2][threadIdx.x] + red[3][threadIdx.x];
}

__global__ __launch_bounds__(256) void k_apply_atomic(
    const float* __restrict__ x,
    const int* __restrict__ srci, const int* __restrict__ tgti,
    const float* __restrict__ W, const float* __restrict__ ab,
    float* __restrict__ out, int E)
{
    const int e = blockIdx.x * 256 + threadIdx.x;
    if (e >= E) return;
    const int s = srci[e], t = tgti[e];
    const float4* ps = (const float4*)(x + (size_t)s * NCH);
    const float4* pt = (const float4*)(x + (size_t)t * NCH);
    float xs[NCH], dx[NCH];
#pragma unroll
    for (int i = 0; i < 8; ++i) {
        float4 a = ps[i], bb = pt[i];
        xs[4*i+0] = a.x; xs[4*i+1] = a.y; xs[4*i+2] = a.z; xs[4*i+3] = a.w;
        dx[4*i+0] = bb.x - a.x; dx[4*i+1] = bb.y - a.y;
        dx[4*i+2] = bb.z - a.z; dx[4*i+3] = bb.w - a.w;
    }
    float* orow = out + (size_t)s * NCH;
#pragma unroll
    for (int c = 0; c < NCH; ++c) {
        const float* wr = W + c * 64;
        float y = 0.f;
#pragma unroll
        for (int k = 0; k < NCH; ++k) y = fmaf(wr[k], xs[k], y);
#pragma unroll
        for (int k = 0; k < NCH; ++k) y = fmaf(wr[32 + k], dx[k], y);
        float z = fmaf(ab[c], y, ab[32 + c]);
        z = (z > 0.f) ? z : (__expf(z) - 1.0f);
        atomicAdd(orow + c, z);
    }
}

// ===========================================================================
extern "C" void kernel_launch(void* const* d_in, const int* in_sizes, int n_in,
                              void* d_out, int out_size, void* d_ws, size_t ws_size,
                              hipStream_t stream)
{
    const float* x     = (const float*)d_in[0];
    const int*   ei    = (const int*)d_in[1];
    const float* W     = (const float*)d_in[2];
    const float* gamma = (const float*)d_in[3];
    const float* beta  = (const float*)d_in[4];
    const int E = in_sizes[1] / 2;
    const int N = in_sizes[0] / NCH;
    const int* srci = ei;
    const int* tgti = ei + E;

    // cooperative grid size (cached): co-resident blocks of 256 threads
    static int coopBlocks = -2;   // -2 = uninit, 0 = unusable
    if (coopBlocks == -2) {
        int nb = 0;
        hipError_t e1 = hipOccupancyMaxActiveBlocksPerMultiprocessor(&nb, k_fused, 256, 0);
        int nCU = 256;
        hipDeviceProp_t prop;
        int dev = 0;
        if (hipGetDevice(&dev) == hipSuccess &&
            hipGetDeviceProperties(&prop, dev) == hipSuccess &&
            prop.multiProcessorCount > 0)
            nCU = prop.multiProcessorCount;
        if (e1 != hipSuccess || nb < 1) coopBlocks = 0;
        else {
            long long g = (long long)nb * nCU;
            coopBlocks = (int)((g > 2048) ? 2048 : g);
            if (coopBlocks < 64) coopBlocks = 0;
        }
    }

    const int GB = (coopBlocks > 0) ? coopBlocks : 2048;

    // ws layout: uh,vh (bf16) | uq,vq (fp8) | outh (bf16x2) | partials | ab
    ushort_t* uh      = (ushort_t*)d_ws;
    ushort_t* vh      = uh + (size_t)N * NCH;
    uchar_t*  uq      = (uchar_t*)(vh + (size_t)N * NCH);
    uchar_t*  vq      = uq + (size_t)N * NCH;
    __hip_bfloat162* outh = (__hip_bfloat162*)(vq + (size_t)N * NCH);
    float*    partials= (float*)((ushort_t*)outh + (size_t)N * NCH);
    float*    ab      = partials + (size_t)2048 * 64;
    const size_t need = (size_t)((char*)(ab + 64) - (char*)d_ws);

    if (ws_size >= need && coopBlocks > 0) {
        int Nv = N, Ev = E;
        void* args[] = {
            (void*)&x, (void*)&srci, (void*)&tgti, (void*)&W,
            (void*)&gamma, (void*)&beta,
            (void*)&uh, (void*)&vh, (void*)&uq, (void*)&vq,
            (void*)&outh, (void*)&partials, (void*)&ab,
            (void*)&d_out, (void*)&Nv, (void*)&Ev
        };
        hipError_t err = hipLaunchCooperativeKernel(
            (const void*)k_fused, dim3(coopBlocks), dim3(256), args, 0, stream);
        if (err == hipSuccess) return;
        coopBlocks = 0;   // remember; fall through to sequence
        (void)GB;
    }

    if (ws_size >= need) {
        // FALLBACK A: r13 proven sequence
        const int SB = 1024;
        const int AB = 2048;
        hipMemsetAsync(outh, 0, (size_t)N * NCH * 2, stream);
        k_uv3<<<(N + 7) / 8, 256, 0, stream>>>(x, W, uh, vh, uq, vq, N);
        k_stats8<<<SB, 256, 0, stream>>>(uq, vq, srci, tgti, partials, E);
        k_finalize<<<1, 256, 0, stream>>>(partials, SB, gamma, beta, ab, 1.0f / (float)E);
        k_apply_pk<<<AB, 256, 0, stream>>>(uh, vh, srci, tgti, ab, outh, E);
        k_cvt<<<(N * 16 + 255) / 256, 256, 0, stream>>>((const uint_t*)outh,
                                                        (float*)d_out, N * 16);
    } else {
        // FALLBACK B: round-1 path
        const int SBf = 512;
        float* abf      = (float*)d_ws;
        float* partialsf = abf + 64;
        hipMemsetAsync(d_out, 0, (size_t)out_size * sizeof(float), stream);
        k_stats_hist<<<SBf, 256, 0, stream>>>(x, srci, tgti, W, partialsf, E);
        k_finalize<<<1, 256, 0, stream>>>(partialsf, SBf, gamma, beta, abf, 1.0f / (float)E);
        k_apply_atomic<<<(E + 255) / 256, 256, 0, stream>>>(x, srci, tgti, W, abf,
                                                            (float*)d_out, E);
    }
}

// Round 7
// 501.108 us; speedup vs baseline: 2.1662x; 2.1662x over previous
//
#include <hip/hip_runtime.h>
#include <hip/hip_bf16.h>
#include <math.h>

#define NCH 32

typedef unsigned short ushort_t;
typedef unsigned int uint_t;
typedef unsigned char uchar_t;

static __device__ __forceinline__ float bf2f(ushort_t b) {
    return __uint_as_float(((uint_t)b) << 16);
}
static __device__ __forceinline__ ushort_t f2bf(float f) {
    __hip_bfloat16 h = __float2bfloat16(f);
    return *reinterpret_cast<ushort_t*>(&h);
}

using f32x2 = __attribute__((ext_vector_type(2))) float;

// --- packed bf16 global atomic with compile-safe fallback ------------------
template <typename T>
__device__ __forceinline__ auto pkAddImpl(T* p, T v, int)
    -> decltype(unsafeAtomicAdd(p, v), void()) {
    unsafeAtomicAdd(p, v);
}
template <typename T>
__device__ void pkAddImpl(T* p, T v, long) {
    uint_t* q = reinterpret_cast<uint_t*>(p);
    uint_t vv = *reinterpret_cast<uint_t*>(&v);
    uint_t cur = *q;
    while (true) {
        float lo = bf2f((ushort_t)(cur & 0xFFFF)) + bf2f((ushort_t)(vv & 0xFFFF));
        float hi = bf2f((ushort_t)(cur >> 16)) + bf2f((ushort_t)(vv >> 16));
        uint_t nw = (uint_t)f2bf(lo) | ((uint_t)f2bf(hi) << 16);
        uint_t prev = atomicCAS(q, cur, nw);
        if (prev == cur) break;
        cur = prev;
    }
}
static __device__ __forceinline__ void pkAdd(__hip_bfloat162* p, float z0, float z1) {
    __hip_bfloat162 v;
    v.x = __float2bfloat16(z0);
    v.y = __float2bfloat16(z1);
    pkAddImpl(p, v, 0);
}

// ===========================================================================
// Round-20: back to the proven r13 pipeline + three attributable changes.
//   r19 post-mortem: cooperative fusion = 1905us (grid.sync cost ~1.7ms,
//   all pipes idle) — coop dead on this chip, but it PROVED threadfence +
//   device-atomic visibility across XCDs is correct.
//   Changes vs r13 (309us, ~100us of it inter-dispatch overhead over 6
//   launches):
//   1. memset folded into k_uv3z (grid-stride zero of outh)     [-1 launch]
//   2. finalize folded into k_stats8f (last-block ticket,
//      mechanism correctness proven by r19)                     [-1 launch]
//   3. k_apply_xcd: blockIdx&7 src-bucket filter (r16-proven
//      mechanism: single-L2 dirty lines -> WRITE 100->~15MB,
//      u-window+out-window L2-resident). Inner body verbatim r13.
// ===========================================================================

// --- u,v (bf16 + fp8) + zero outh + zero ticket ----------------------------
__global__ __launch_bounds__(256) void k_uv3z(
    const float* __restrict__ x, const float* __restrict__ W,
    ushort_t* __restrict__ uh, ushort_t* __restrict__ vh,
    uchar_t* __restrict__ uq, uchar_t* __restrict__ vq,
    uint_t* __restrict__ outh32, int* __restrict__ ticket, int N)
{
    __shared__ float At[NCH * NCH];   // At[k*32+c] = W[c][k] - W[c][32+k]
    __shared__ float Bt[NCH * NCH];   // Bt[k*32+c] = W[c][32+k]
    for (int i = threadIdx.x; i < NCH * NCH; i += 256) {
        const int k = i >> 5, c = i & 31;
        const float w1 = W[c * 64 + k];
        const float w2 = W[c * 64 + 32 + k];
        At[i] = w1 - w2;
        Bt[i] = w2;
    }

    // zero outh (grid-stride) + ticket; no sync needed vs uv part
    {
        const int M = N * 16;
        for (int i = blockIdx.x * 256 + threadIdx.x; i < M; i += gridDim.x * 256)
            outh32[i] = 0u;
        if (blockIdx.x == 0 && threadIdx.x == 0) *ticket = 0;
    }
    __syncthreads();

    const int n = blockIdx.x * 8 + (threadIdx.x >> 5);
    const int c = threadIdx.x & 31;
    if (n >= N) return;
    const float xc = x[(size_t)n * NCH + c];
    float su = 0.f, sv = 0.f;
#pragma unroll
    for (int k = 0; k < NCH; ++k) {
        const float xk = __shfl(xc, k, 32);
        su = fmaf(At[k * 32 + c], xk, su);
        sv = fmaf(Bt[k * 32 + c], xk, sv);
    }
    uh[(size_t)n * NCH + c] = f2bf(su);
    vh[(size_t)n * NCH + c] = f2bf(sv);
    uq[(size_t)n * NCH + c] =
        (uchar_t)(__builtin_amdgcn_cvt_pk_fp8_f32(su, su, 0, false) & 0xFF);
    vq[(size_t)n * NCH + c] =
        (uchar_t)(__builtin_amdgcn_cvt_pk_fp8_f32(sv, sv, 0, false) & 0xFF);
}

// --- stats over fp8 + fused finalize (last-block ticket) -------------------
__global__ __launch_bounds__(256) void k_stats8f(
    const uchar_t* __restrict__ uq, const uchar_t* __restrict__ vq,
    const int* __restrict__ srci, const int* __restrict__ tgti,
    float* __restrict__ partials, int* __restrict__ ticket,
    const float* __restrict__ gamma, const float* __restrict__ beta,
    float* __restrict__ ab, float invE, int E)
{
    const ushort_t* __restrict__ uq16 = (const ushort_t*)uq;
    const ushort_t* __restrict__ vq16 = (const ushort_t*)vq;
    const int l  = threadIdx.x & 15;
    const int g  = (blockIdx.x * 256 + threadIdx.x) >> 4;
    const int nG = (gridDim.x * 256) >> 4;

    float s0 = 0.f, s1 = 0.f, q0 = 0.f, q1 = 0.f;
    int e = g;
    for (; e + 3 * nG < E; e += 4 * nG) {
        const int ea = e, eb = e + nG, ec = e + 2 * nG, ed = e + 3 * nG;
        const int sa = srci[ea], sb = srci[eb], sc = srci[ec], sd = srci[ed];
        const int ta = tgti[ea], tb = tgti[eb], tc = tgti[ec], td = tgti[ed];
        const ushort_t ua = uq16[(size_t)sa * 16 + l];
        const ushort_t ub = uq16[(size_t)sb * 16 + l];
        const ushort_t uc = uq16[(size_t)sc * 16 + l];
        const ushort_t ud = uq16[(size_t)sd * 16 + l];
        const ushort_t va = vq16[(size_t)ta * 16 + l];
        const ushort_t vb = vq16[(size_t)tb * 16 + l];
        const ushort_t vc = vq16[(size_t)tc * 16 + l];
        const ushort_t vd = vq16[(size_t)td * 16 + l];
#pragma unroll
        for (int k = 0; k < 4; ++k) {
            const ushort_t uu = (k == 0) ? ua : (k == 1) ? ub : (k == 2) ? uc : ud;
            const ushort_t vv = (k == 0) ? va : (k == 1) ? vb : (k == 2) ? vc : vd;
            const f32x2 uf = __builtin_amdgcn_cvt_pk_f32_fp8((int)uu, false);
            const f32x2 vf = __builtin_amdgcn_cvt_pk_f32_fp8((int)vv, false);
            const float y0 = uf.x + vf.x;
            const float y1 = uf.y + vf.y;
            s0 += y0; q0 = fmaf(y0, y0, q0);
            s1 += y1; q1 = fmaf(y1, y1, q1);
        }
    }
    for (; e < E; e += nG) {
        const int s = srci[e], t = tgti[e];
        const f32x2 uf = __builtin_amdgcn_cvt_pk_f32_fp8((int)uq16[(size_t)s * 16 + l], false);
        const f32x2 vf = __builtin_amdgcn_cvt_pk_f32_fp8((int)vq16[(size_t)t * 16 + l], false);
        const float y0 = uf.x + vf.x;
        const float y1 = uf.y + vf.y;
        s0 += y0; q0 = fmaf(y0, y0, q0);
        s1 += y1; q1 = fmaf(y1, y1, q1);
    }

    __shared__ float sL[16][32];
    __shared__ float qL[16][32];
    const int grp = threadIdx.x >> 4;
    sL[grp][2 * l + 0] = s0;
    sL[grp][2 * l + 1] = s1;
    qL[grp][2 * l + 0] = q0;
    qL[grp][2 * l + 1] = q1;
    __syncthreads();
    if (threadIdx.x < 32) {
        float a = 0.f;
#pragma unroll
        for (int r = 0; r < 16; ++r) a += sL[r][threadIdx.x];
        partials[(size_t)blockIdx.x * 64 + threadIdx.x] = a;
    } else if (threadIdx.x < 64) {
        const int cc = threadIdx.x - 32;
        float a = 0.f;
#pragma unroll
        for (int r = 0; r < 16; ++r) a += qL[r][cc];
        partials[(size_t)blockIdx.x * 64 + 32 + cc] = a;
    }

    // ---- last-block finalize (device-scope fence + ticket; r19-proven) ----
    __shared__ int isLast;
    __threadfence();
    __syncthreads();
    if (threadIdx.x == 0) {
        const int prev = atomicAdd(ticket, 1);
        isLast = (prev == (int)gridDim.x - 1) ? 1 : 0;
    }
    __syncthreads();
    if (isLast) {
        __shared__ float acc[4][64];
        const int vtx = threadIdx.x & 63, chunk = threadIdx.x >> 6;
        float s = 0.f;
        for (int r = chunk; r < (int)gridDim.x; r += 4)
            s += partials[(size_t)r * 64 + vtx];
        acc[chunk][vtx] = s;
        __syncthreads();
        if (threadIdx.x < 64)
            acc[0][vtx] = acc[0][vtx] + acc[1][vtx] + acc[2][vtx] + acc[3][vtx];
        __syncthreads();
        if (threadIdx.x < 32) {
            const int c = threadIdx.x;
            float mean = acc[0][c] * invE;
            float var  = acc[0][32 + c] * invE - mean * mean;
            float rstd = rsqrtf(var + 1e-5f);
            float a = gamma[c] * rstd;
            ab[c] = a; ab[32 + c] = beta[c] - mean * a;
        }
    }
}

// --- apply: XCD src-bucket filter + pk-bf16 atomics (body verbatim r13) ----
__global__ __launch_bounds__(256) void k_apply_xcd(
    const ushort_t* __restrict__ uh, const ushort_t* __restrict__ vh,
    const int* __restrict__ srci, const int* __restrict__ tgti,
    const float* __restrict__ ab,
    __hip_bfloat162* __restrict__ outh, int E, int NS)
{
    const uint_t* __restrict__ uh32 = (const uint_t*)uh;
    const uint_t* __restrict__ vh32 = (const uint_t*)vh;
    const int l  = threadIdx.x & 15;
    const float a0 = ab[2 * l + 0], a1 = ab[2 * l + 1];
    const float b0 = ab[32 + 2 * l + 0], b1 = ab[32 + 2 * l + 1];

    const int xb = blockIdx.x & 7;           // XCD bucket (r16-proven heuristic)
    const int lo = xb * NS;
    const int bi = blockIdx.x >> 3;
    const int nb = gridDim.x >> 3;           // blocks per bucket set
    const int g  = (bi * 256 + threadIdx.x) >> 4;
    const int nG = nb * 16;                  // groups per bucket set

    int e = g;
    for (; e + 3 * nG < E; e += 4 * nG) {
        const int ea = e, eb = e + nG, ec = e + 2 * nG, ed = e + 3 * nG;
        const int sa = srci[ea], sb = srci[eb], sc = srci[ec], sd = srci[ed];
        const bool ma = (unsigned)(sa - lo) < (unsigned)NS;
        const bool mb = (unsigned)(sb - lo) < (unsigned)NS;
        const bool mc = (unsigned)(sc - lo) < (unsigned)NS;
        const bool md = (unsigned)(sd - lo) < (unsigned)NS;
        if (ma) {
            const uint_t U = uh32[(size_t)sa * 16 + l];
            const uint_t V = vh32[(size_t)tgti[ea] * 16 + l];
            const float y0 = bf2f((ushort_t)(U & 0xFFFF)) + bf2f((ushort_t)(V & 0xFFFF));
            const float y1 = bf2f((ushort_t)(U >> 16))    + bf2f((ushort_t)(V >> 16));
            float z0 = fmaf(a0, y0, b0);
            float z1 = fmaf(a1, y1, b1);
            z0 = (z0 > 0.f) ? z0 : (__expf(z0) - 1.0f);
            z1 = (z1 > 0.f) ? z1 : (__expf(z1) - 1.0f);
            pkAdd(&outh[(size_t)sa * 16 + l], z0, z1);
        }
        if (mb) {
            const uint_t U = uh32[(size_t)sb * 16 + l];
            const uint_t V = vh32[(size_t)tgti[eb] * 16 + l];
            const float y0 = bf2f((ushort_t)(U & 0xFFFF)) + bf2f((ushort_t)(V & 0xFFFF));
            const float y1 = bf2f((ushort_t)(U >> 16))    + bf2f((ushort_t)(V >> 16));
            float z0 = fmaf(a0, y0, b0);
            float z1 = fmaf(a1, y1, b1);
            z0 = (z0 > 0.f) ? z0 : (__expf(z0) - 1.0f);
            z1 = (z1 > 0.f) ? z1 : (__expf(z1) - 1.0f);
            pkAdd(&outh[(size_t)sb * 16 + l], z0, z1);
        }
        if (mc) {
            const uint_t U = uh32[(size_t)sc * 16 + l];
            const uint_t V = vh32[(size_t)tgti[ec] * 16 + l];
            const float y0 = bf2f((ushort_t)(U & 0xFFFF)) + bf2f((ushort_t)(V & 0xFFFF));
            const float y1 = bf2f((ushort_t)(U >> 16))    + bf2f((ushort_t)(V >> 16));
            float z0 = fmaf(a0, y0, b0);
            float z1 = fmaf(a1, y1, b1);
            z0 = (z0 > 0.f) ? z0 : (__expf(z0) - 1.0f);
            z1 = (z1 > 0.f) ? z1 : (__expf(z1) - 1.0f);
            pkAdd(&outh[(size_t)sc * 16 + l], z0, z1);
        }
        if (md) {
            const uint_t U = uh32[(size_t)sd * 16 + l];
            const uint_t V = vh32[(size_t)tgti[ed] * 16 + l];
            const float y0 = bf2f((ushort_t)(U & 0xFFFF)) + bf2f((ushort_t)(V & 0xFFFF));
            const float y1 = bf2f((ushort_t)(U >> 16))    + bf2f((ushort_t)(V >> 16));
            float z0 = fmaf(a0, y0, b0);
            float z1 = fmaf(a1, y1, b1);
            z0 = (z0 > 0.f) ? z0 : (__expf(z0) - 1.0f);
            z1 = (z1 > 0.f) ? z1 : (__expf(z1) - 1.0f);
            pkAdd(&outh[(size_t)sd * 16 + l], z0, z1);
        }
    }
    for (; e < E; e += nG) {
        const int s = srci[e];
        if ((unsigned)(s - lo) < (unsigned)NS) {
            const uint_t U = uh32[(size_t)s * 16 + l];
            const uint_t V = vh32[(size_t)tgti[e] * 16 + l];
            const float y0 = bf2f((ushort_t)(U & 0xFFFF)) + bf2f((ushort_t)(V & 0xFFFF));
            const float y1 = bf2f((ushort_t)(U >> 16))    + bf2f((ushort_t)(V >> 16));
            float z0 = fmaf(a0, y0, b0);
            float z1 = fmaf(a1, y1, b1);
            z0 = (z0 > 0.f) ? z0 : (__expf(z0) - 1.0f);
            z1 = (z1 > 0.f) ? z1 : (__expf(z1) - 1.0f);
            pkAdd(&outh[(size_t)s * 16 + l], z0, z1);
        }
    }
}

// --- convert bf16 accumulator -> fp32 out ----------------------------------
__global__ __launch_bounds__(256) void k_cvt(
    const uint_t* __restrict__ outh32, float* __restrict__ out, int M)
{
    const int i = blockIdx.x * 256 + threadIdx.x;
    if (i >= M) return;
    const uint_t w = outh32[i];
    float2 f;
    f.x = bf2f((ushort_t)(w & 0xFFFF));
    f.y = bf2f((ushort_t)(w >> 16));
    ((float2*)out)[i] = f;
}

// ===========================================================================
// FALLBACK (round-1 proven path) — only if ws too small
// ===========================================================================
__global__ __launch_bounds__(256) void k_stats_hist(
    const float* __restrict__ x,
    const int* __restrict__ srci, const int* __restrict__ tgti,
    const float* __restrict__ W,
    float* __restrict__ partials, int E)
{
    float sum[NCH], ssq[NCH];
#pragma unroll
    for (int c = 0; c < NCH; ++c) { sum[c] = 0.f; ssq[c] = 0.f; }
    const int stride = gridDim.x * blockDim.x;
    for (int e = blockIdx.x * blockDim.x + threadIdx.x; e < E; e += stride) {
        const int s = srci[e], t = tgti[e];
        const float4* ps = (const float4*)(x + (size_t)s * NCH);
        const float4* pt = (const float4*)(x + (size_t)t * NCH);
        float xs[NCH], dx[NCH];
#pragma unroll
        for (int i = 0; i < 8; ++i) {
            float4 a = ps[i], bb = pt[i];
            xs[4*i+0] = a.x; xs[4*i+1] = a.y; xs[4*i+2] = a.z; xs[4*i+3] = a.w;
            dx[4*i+0] = bb.x - a.x; dx[4*i+1] = bb.y - a.y;
            dx[4*i+2] = bb.z - a.z; dx[4*i+3] = bb.w - a.w;
        }
#pragma unroll
        for (int c = 0; c < NCH; ++c) {
            const float* wr = W + c * 64;
            float y = 0.f;
#pragma unroll
            for (int k = 0; k < NCH; ++k) y = fmaf(wr[k], xs[k], y);
#pragma unroll
            for (int k = 0; k < NCH; ++k) y = fmaf(wr[32 + k], dx[k], y);
            sum[c] += y;
            ssq[c] = fmaf(y, y, ssq[c]);
        }
    }
#pragma unroll
    for (int c = 0; c < NCH; ++c) {
#pragma unroll
        for (int off = 32; off > 0; off >>= 1) {
            sum[c] += __shfl_down(sum[c], off);
            ssq[c] += __shfl_down(ssq[c], off);
        }
    }
    __shared__ float red[4][64];
    const int lane = threadIdx.x & 63, wave = threadIdx.x >> 6;
    if (lane == 0) {
#pragma unroll
        for (int c = 0; c < NCH; ++c) { red[wave][c] = sum[c]; red[wave][NCH+c] = ssq[c]; }
    }
    __syncthreads();
    if (threadIdx.x < 64)
        partials[(size_t)blockIdx.x * 64 + threadIdx.x] =
            red[0][threadIdx.x] + red[1][threadIdx.x] + red[2][threadIdx.x] + red[3][threadIdx.x];
}

__global__ __launch_bounds__(256) void k_finalize(
    const float* __restrict__ partials, int nblocks,
    const float* __restrict__ gamma, const float* __restrict__ beta,
    float* __restrict__ ab, float invE)
{
    __shared__ float acc[4][64];
    const int vtx = threadIdx.x & 63, chunk = threadIdx.x >> 6;
    float s = 0.f;
    for (int r = chunk; r < nblocks; r += 4) s += partials[(size_t)r * 64 + vtx];
    acc[chunk][vtx] = s;
    __syncthreads();
    if (threadIdx.x < 64) acc[0][vtx] = acc[0][vtx] + acc[1][vtx] + acc[2][vtx] + acc[3][vtx];
    __syncthreads();
    if (threadIdx.x < 32) {
        const int c = threadIdx.x;
        float mean = acc[0][c] * invE;
        float var  = acc[0][32 + c] * invE - mean * mean;
        float rstd = rsqrtf(var + 1e-5f);
        float a = gamma[c] * rstd;
        ab[c] = a; ab[32 + c] = beta[c] - mean * a;
    }
}

__global__ __launch_bounds__(256) void k_apply_atomic(
    const float* __restrict__ x,
    const int* __restrict__ srci, const int* __restrict__ tgti,
    const float* __restrict__ W, const float* __restrict__ ab,
    float* __restrict__ out, int E)
{
    const int e = blockIdx.x * 256 + threadIdx.x;
    if (e >= E) return;
    const int s = srci[e], t = tgti[e];
    const float4* ps = (const float4*)(x + (size_t)s * NCH);
    const float4* pt = (const float4*)(x + (size_t)t * NCH);
    float xs[NCH], dx[NCH];
#pragma unroll
    for (int i = 0; i < 8; ++i) {
        float4 a = ps[i], bb = pt[i];
        xs[4*i+0] = a.x; xs[4*i+1] = a.y; xs[4*i+2] = a.z; xs[4*i+3] = a.w;
        dx[4*i+0] = bb.x - a.x; dx[4*i+1] = bb.y - a.y;
        dx[4*i+2] = bb.z - a.z; dx[4*i+3] = bb.w - a.w;
    }
    float* orow = out + (size_t)s * NCH;
#pragma unroll
    for (int c = 0; c < NCH; ++c) {
        const float* wr = W + c * 64;
        float y = 0.f;
#pragma unroll
        for (int k = 0; k < NCH; ++k) y = fmaf(wr[k], xs[k], y);
#pragma unroll
        for (int k = 0; k < NCH; ++k) y = fmaf(wr[32 + k], dx[k], y);
        float z = fmaf(ab[c], y, ab[32 + c]);
        z = (z > 0.f) ? z : (__expf(z) - 1.0f);
        atomicAdd(orow + c, z);
    }
}

// ===========================================================================
extern "C" void kernel_launch(void* const* d_in, const int* in_sizes, int n_in,
                              void* d_out, int out_size, void* d_ws, size_t ws_size,
                              hipStream_t stream)
{
    const float* x     = (const float*)d_in[0];
    const int*   ei    = (const int*)d_in[1];
    const float* W     = (const float*)d_in[2];
    const float* gamma = (const float*)d_in[3];
    const float* beta  = (const float*)d_in[4];
    const int E = in_sizes[1] / 2;
    const int N = in_sizes[0] / NCH;
    const int* srci = ei;
    const int* tgti = ei + E;

    const int SB = 1024;           // stats grid
    const int AB = 2048;           // apply grid (multiple of 8)
    const int NS = (N + 7) / 8;    // nodes per XCD bucket

    // ws layout: uh,vh (bf16) | uq,vq (fp8) | outh (bf16x2) | partials | ab | ticket
    ushort_t* uh      = (ushort_t*)d_ws;
    ushort_t* vh      = uh + (size_t)N * NCH;
    uchar_t*  uq      = (uchar_t*)(vh + (size_t)N * NCH);
    uchar_t*  vq      = uq + (size_t)N * NCH;
    __hip_bfloat162* outh = (__hip_bfloat162*)(vq + (size_t)N * NCH);
    float*    partials= (float*)((ushort_t*)outh + (size_t)N * NCH);
    float*    ab      = partials + (size_t)SB * 64;
    int*      ticket  = (int*)(ab + 64);
    const size_t need = (size_t)((char*)(ticket + 1) - (char*)d_ws);

    if (ws_size >= need) {
        k_uv3z<<<(N + 7) / 8, 256, 0, stream>>>(x, W, uh, vh, uq, vq,
                                                (uint_t*)outh, ticket, N);
        k_stats8f<<<SB, 256, 0, stream>>>(uq, vq, srci, tgti, partials, ticket,
                                          gamma, beta, ab, 1.0f / (float)E, E);
        k_apply_xcd<<<AB, 256, 0, stream>>>(uh, vh, srci, tgti, ab, outh, E, NS);
        k_cvt<<<(N * 16 + 255) / 256, 256, 0, stream>>>((const uint_t*)outh,
                                                        (float*)d_out, N * 16);
    } else {
        const int SBf = 512;
        float* abf      = (float*)d_ws;
        float* partialsf = abf + 64;
        hipMemsetAsync(d_out, 0, (size_t)out_size * sizeof(float), stream);
        k_stats_hist<<<SBf, 256, 0, stream>>>(x, srci, tgti, W, partialsf, E);
        k_finalize<<<1, 256, 0, stream>>>(partialsf, SBf, gamma, beta, abf, 1.0f / (float)E);
        k_apply_atomic<<<(E + 255) / 256, 256, 0, stream>>>(x, srci, tgti, W, abf,
                                                            (float*)d_out, E);
    }
}

// Round 8
// 385.469 us; speedup vs baseline: 2.8160x; 1.3000x over previous
//
#include <hip/hip_runtime.h>
#include <hip/hip_bf16.h>
#include <math.h>

#define NCH 32

typedef unsigned short ushort_t;
typedef unsigned int uint_t;
typedef unsigned char uchar_t;

static __device__ __forceinline__ float bf2f(ushort_t b) {
    return __uint_as_float(((uint_t)b) << 16);
}
static __device__ __forceinline__ ushort_t f2bf(float f) {
    __hip_bfloat16 h = __float2bfloat16(f);
    return *reinterpret_cast<ushort_t*>(&h);
}

using f32x2 = __attribute__((ext_vector_type(2))) float;

// --- packed bf16 global atomic with compile-safe fallback ------------------
template <typename T>
__device__ __forceinline__ auto pkAddImpl(T* p, T v, int)
    -> decltype(unsafeAtomicAdd(p, v), void()) {
    unsafeAtomicAdd(p, v);
}
template <typename T>
__device__ void pkAddImpl(T* p, T v, long) {
    uint_t* q = reinterpret_cast<uint_t*>(p);
    uint_t vv = *reinterpret_cast<uint_t*>(&v);
    uint_t cur = *q;
    while (true) {
        float lo = bf2f((ushort_t)(cur & 0xFFFF)) + bf2f((ushort_t)(vv & 0xFFFF));
        float hi = bf2f((ushort_t)(cur >> 16)) + bf2f((ushort_t)(vv >> 16));
        uint_t nw = (uint_t)f2bf(lo) | ((uint_t)f2bf(hi) << 16);
        uint_t prev = atomicCAS(q, cur, nw);
        if (prev == cur) break;
        cur = prev;
    }
}
static __device__ __forceinline__ void pkAdd(__hip_bfloat162* p, float z0, float z1) {
    __hip_bfloat162 v;
    v.x = __float2bfloat16(z0);
    v.y = __float2bfloat16(z1);
    pkAddImpl(p, v, 0);
}

// ===========================================================================
// Round-21: revert apply to verbatim r13 k_apply_pk; keep the two fusions.
//   r20 post-mortem: k_apply_xcd WRITE_SIZE = 100001 KB — IDENTICAL to the
//   unfiltered r13 apply. pk-atomics are memory-side with 4B-sector write
//   accounting; L2 bucketing cannot reduce atomic traffic (r16's mechanism
//   applies to cached plain stores only). Filter cost 8x edge re-scan +
//   divergence: 206us vs 87us. Reverted.
//   Kernel sums (~318) vs total (501) left ~180us unattributed; with apply
//   back at 87us, this round's top-5 will expose k_stats8f's true cost:
//   ~87us => ticket-finalize fusion is free; >>87 => fence is the cost and
//   r22 drops it.
//   Known floors on this chip: stats ~86us (random 32B-gather rate),
//   apply ~87us (atomic rate; WRITE 100MB immutable), uv ~10, cvt ~13.
// ===========================================================================

// --- u,v (bf16 + fp8) + zero outh + zero ticket ----------------------------
__global__ __launch_bounds__(256) void k_uv3z(
    const float* __restrict__ x, const float* __restrict__ W,
    ushort_t* __restrict__ uh, ushort_t* __restrict__ vh,
    uchar_t* __restrict__ uq, uchar_t* __restrict__ vq,
    uint_t* __restrict__ outh32, int* __restrict__ ticket, int N)
{
    __shared__ float At[NCH * NCH];   // At[k*32+c] = W[c][k] - W[c][32+k]
    __shared__ float Bt[NCH * NCH];   // Bt[k*32+c] = W[c][32+k]
    for (int i = threadIdx.x; i < NCH * NCH; i += 256) {
        const int k = i >> 5, c = i & 31;
        const float w1 = W[c * 64 + k];
        const float w2 = W[c * 64 + 32 + k];
        At[i] = w1 - w2;
        Bt[i] = w2;
    }

    // zero outh (grid-stride) + ticket; independent of the uv part
    {
        const int M = N * 16;
        for (int i = blockIdx.x * 256 + threadIdx.x; i < M; i += gridDim.x * 256)
            outh32[i] = 0u;
        if (blockIdx.x == 0 && threadIdx.x == 0) *ticket = 0;
    }
    __syncthreads();

    const int n = blockIdx.x * 8 + (threadIdx.x >> 5);
    const int c = threadIdx.x & 31;
    if (n >= N) return;
    const float xc = x[(size_t)n * NCH + c];
    float su = 0.f, sv = 0.f;
#pragma unroll
    for (int k = 0; k < NCH; ++k) {
        const float xk = __shfl(xc, k, 32);
        su = fmaf(At[k * 32 + c], xk, su);
        sv = fmaf(Bt[k * 32 + c], xk, sv);
    }
    uh[(size_t)n * NCH + c] = f2bf(su);
    vh[(size_t)n * NCH + c] = f2bf(sv);
    uq[(size_t)n * NCH + c] =
        (uchar_t)(__builtin_amdgcn_cvt_pk_fp8_f32(su, su, 0, false) & 0xFF);
    vq[(size_t)n * NCH + c] =
        (uchar_t)(__builtin_amdgcn_cvt_pk_fp8_f32(sv, sv, 0, false) & 0xFF);
}

// --- stats over fp8 + fused finalize (last-block ticket) -------------------
__global__ __launch_bounds__(256) void k_stats8f(
    const uchar_t* __restrict__ uq, const uchar_t* __restrict__ vq,
    const int* __restrict__ srci, const int* __restrict__ tgti,
    float* __restrict__ partials, int* __restrict__ ticket,
    const float* __restrict__ gamma, const float* __restrict__ beta,
    float* __restrict__ ab, float invE, int E)
{
    const ushort_t* __restrict__ uq16 = (const ushort_t*)uq;
    const ushort_t* __restrict__ vq16 = (const ushort_t*)vq;
    const int l  = threadIdx.x & 15;
    const int g  = (blockIdx.x * 256 + threadIdx.x) >> 4;
    const int nG = (gridDim.x * 256) >> 4;

    float s0 = 0.f, s1 = 0.f, q0 = 0.f, q1 = 0.f;
    int e = g;
    for (; e + 3 * nG < E; e += 4 * nG) {
        const int ea = e, eb = e + nG, ec = e + 2 * nG, ed = e + 3 * nG;
        const int sa = srci[ea], sb = srci[eb], sc = srci[ec], sd = srci[ed];
        const int ta = tgti[ea], tb = tgti[eb], tc = tgti[ec], td = tgti[ed];
        const ushort_t ua = uq16[(size_t)sa * 16 + l];
        const ushort_t ub = uq16[(size_t)sb * 16 + l];
        const ushort_t uc = uq16[(size_t)sc * 16 + l];
        const ushort_t ud = uq16[(size_t)sd * 16 + l];
        const ushort_t va = vq16[(size_t)ta * 16 + l];
        const ushort_t vb = vq16[(size_t)tb * 16 + l];
        const ushort_t vc = vq16[(size_t)tc * 16 + l];
        const ushort_t vd = vq16[(size_t)td * 16 + l];
#pragma unroll
        for (int k = 0; k < 4; ++k) {
            const ushort_t uu = (k == 0) ? ua : (k == 1) ? ub : (k == 2) ? uc : ud;
            const ushort_t vv = (k == 0) ? va : (k == 1) ? vb : (k == 2) ? vc : vd;
            const f32x2 uf = __builtin_amdgcn_cvt_pk_f32_fp8((int)uu, false);
            const f32x2 vf = __builtin_amdgcn_cvt_pk_f32_fp8((int)vv, false);
            const float y0 = uf.x + vf.x;
            const float y1 = uf.y + vf.y;
            s0 += y0; q0 = fmaf(y0, y0, q0);
            s1 += y1; q1 = fmaf(y1, y1, q1);
        }
    }
    for (; e < E; e += nG) {
        const int s = srci[e], t = tgti[e];
        const f32x2 uf = __builtin_amdgcn_cvt_pk_f32_fp8((int)uq16[(size_t)s * 16 + l], false);
        const f32x2 vf = __builtin_amdgcn_cvt_pk_f32_fp8((int)vq16[(size_t)t * 16 + l], false);
        const float y0 = uf.x + vf.x;
        const float y1 = uf.y + vf.y;
        s0 += y0; q0 = fmaf(y0, y0, q0);
        s1 += y1; q1 = fmaf(y1, y1, q1);
    }

    __shared__ float sL[16][32];
    __shared__ float qL[16][32];
    const int grp = threadIdx.x >> 4;
    sL[grp][2 * l + 0] = s0;
    sL[grp][2 * l + 1] = s1;
    qL[grp][2 * l + 0] = q0;
    qL[grp][2 * l + 1] = q1;
    __syncthreads();
    if (threadIdx.x < 32) {
        float a = 0.f;
#pragma unroll
        for (int r = 0; r < 16; ++r) a += sL[r][threadIdx.x];
        partials[(size_t)blockIdx.x * 64 + threadIdx.x] = a;
    } else if (threadIdx.x < 64) {
        const int cc = threadIdx.x - 32;
        float a = 0.f;
#pragma unroll
        for (int r = 0; r < 16; ++r) a += qL[r][cc];
        partials[(size_t)blockIdx.x * 64 + 32 + cc] = a;
    }

    // ---- last-block finalize (device-scope fence + ticket) ----------------
    __shared__ int isLast;
    __threadfence();
    __syncthreads();
    if (threadIdx.x == 0) {
        const int prev = atomicAdd(ticket, 1);
        isLast = (prev == (int)gridDim.x - 1) ? 1 : 0;
    }
    __syncthreads();
    if (isLast) {
        __shared__ float acc[4][64];
        const int vtx = threadIdx.x & 63, chunk = threadIdx.x >> 6;
        float s = 0.f;
        for (int r = chunk; r < (int)gridDim.x; r += 4)
            s += partials[(size_t)r * 64 + vtx];
        acc[chunk][vtx] = s;
        __syncthreads();
        if (threadIdx.x < 64)
            acc[0][vtx] = acc[0][vtx] + acc[1][vtx] + acc[2][vtx] + acc[3][vtx];
        __syncthreads();
        if (threadIdx.x < 32) {
            const int c = threadIdx.x;
            float mean = acc[0][c] * invE;
            float var  = acc[0][32 + c] * invE - mean * mean;
            float rstd = rsqrtf(var + 1e-5f);
            float a = gamma[c] * rstd;
            ab[c] = a; ab[32 + c] = beta[c] - mean * a;
        }
    }
}

// --- apply: verbatim r13 k_apply_pk (proven 87us @ 3TB/s) ------------------
__global__ __launch_bounds__(256) void k_apply_pk(
    const ushort_t* __restrict__ uh, const ushort_t* __restrict__ vh,
    const int* __restrict__ srci, const int* __restrict__ tgti,
    const float* __restrict__ ab,
    __hip_bfloat162* __restrict__ outh, int E)
{
    const uint_t* __restrict__ uh32 = (const uint_t*)uh;
    const uint_t* __restrict__ vh32 = (const uint_t*)vh;
    const int l  = threadIdx.x & 15;
    const float a0 = ab[2 * l + 0], a1 = ab[2 * l + 1];
    const float b0 = ab[32 + 2 * l + 0], b1 = ab[32 + 2 * l + 1];
    const int g  = (blockIdx.x * 256 + threadIdx.x) >> 4;
    const int nG = (gridDim.x * 256) >> 4;

    int e = g;
    for (; e + 3 * nG < E; e += 4 * nG) {
        const int ea = e, eb = e + nG, ec = e + 2 * nG, ed = e + 3 * nG;
        const int sa = srci[ea], sb = srci[eb], sc = srci[ec], sd = srci[ed];
        const int ta = tgti[ea], tb = tgti[eb], tc = tgti[ec], td = tgti[ed];
        const uint_t Ua = uh32[(size_t)sa * 16 + l];
        const uint_t Ub = uh32[(size_t)sb * 16 + l];
        const uint_t Uc = uh32[(size_t)sc * 16 + l];
        const uint_t Ud = uh32[(size_t)sd * 16 + l];
        const uint_t Va = vh32[(size_t)ta * 16 + l];
        const uint_t Vb = vh32[(size_t)tb * 16 + l];
        const uint_t Vc = vh32[(size_t)tc * 16 + l];
        const uint_t Vd = vh32[(size_t)td * 16 + l];
        const int ss[4] = {sa, sb, sc, sd};
        const uint_t UU[4] = {Ua, Ub, Uc, Ud};
        const uint_t VV[4] = {Va, Vb, Vc, Vd};
#pragma unroll
        for (int k = 0; k < 4; ++k) {
            const float y0 = bf2f((ushort_t)(UU[k] & 0xFFFF)) + bf2f((ushort_t)(VV[k] & 0xFFFF));
            const float y1 = bf2f((ushort_t)(UU[k] >> 16))    + bf2f((ushort_t)(VV[k] >> 16));
            float z0 = fmaf(a0, y0, b0);
            float z1 = fmaf(a1, y1, b1);
            z0 = (z0 > 0.f) ? z0 : (__expf(z0) - 1.0f);
            z1 = (z1 > 0.f) ? z1 : (__expf(z1) - 1.0f);
            pkAdd(&outh[(size_t)ss[k] * 16 + l], z0, z1);
        }
    }
    for (; e < E; e += nG) {
        const int s = srci[e], t = tgti[e];
        const uint_t U = uh32[(size_t)s * 16 + l];
        const uint_t V = vh32[(size_t)t * 16 + l];
        const float y0 = bf2f((ushort_t)(U & 0xFFFF)) + bf2f((ushort_t)(V & 0xFFFF));
        const float y1 = bf2f((ushort_t)(U >> 16))    + bf2f((ushort_t)(V >> 16));
        float z0 = fmaf(a0, y0, b0);
        float z1 = fmaf(a1, y1, b1);
        z0 = (z0 > 0.f) ? z0 : (__expf(z0) - 1.0f);
        z1 = (z1 > 0.f) ? z1 : (__expf(z1) - 1.0f);
        pkAdd(&outh[(size_t)s * 16 + l], z0, z1);
    }
}

// --- convert bf16 accumulator -> fp32 out ----------------------------------
__global__ __launch_bounds__(256) void k_cvt(
    const uint_t* __restrict__ outh32, float* __restrict__ out, int M)
{
    const int i = blockIdx.x * 256 + threadIdx.x;
    if (i >= M) return;
    const uint_t w = outh32[i];
    float2 f;
    f.x = bf2f((ushort_t)(w & 0xFFFF));
    f.y = bf2f((ushort_t)(w >> 16));
    ((float2*)out)[i] = f;
}

// ===========================================================================
// FALLBACK (round-1 proven path) — only if ws too small
// ===========================================================================
__global__ __launch_bounds__(256) void k_stats_hist(
    const float* __restrict__ x,
    const int* __restrict__ srci, const int* __restrict__ tgti,
    const float* __restrict__ W,
    float* __restrict__ partials, int E)
{
    float sum[NCH], ssq[NCH];
#pragma unroll
    for (int c = 0; c < NCH; ++c) { sum[c] = 0.f; ssq[c] = 0.f; }
    const int stride = gridDim.x * blockDim.x;
    for (int e = blockIdx.x * blockDim.x + threadIdx.x; e < E; e += stride) {
        const int s = srci[e], t = tgti[e];
        const float4* ps = (const float4*)(x + (size_t)s * NCH);
        const float4* pt = (const float4*)(x + (size_t)t * NCH);
        float xs[NCH], dx[NCH];
#pragma unroll
        for (int i = 0; i < 8; ++i) {
            float4 a = ps[i], bb = pt[i];
            xs[4*i+0] = a.x; xs[4*i+1] = a.y; xs[4*i+2] = a.z; xs[4*i+3] = a.w;
            dx[4*i+0] = bb.x - a.x; dx[4*i+1] = bb.y - a.y;
            dx[4*i+2] = bb.z - a.z; dx[4*i+3] = bb.w - a.w;
        }
#pragma unroll
        for (int c = 0; c < NCH; ++c) {
            const float* wr = W + c * 64;
            float y = 0.f;
#pragma unroll
            for (int k = 0; k < NCH; ++k) y = fmaf(wr[k], xs[k], y);
#pragma unroll
            for (int k = 0; k < NCH; ++k) y = fmaf(wr[32 + k], dx[k], y);
            sum[c] += y;
            ssq[c] = fmaf(y, y, ssq[c]);
        }
    }
#pragma unroll
    for (int c = 0; c < NCH; ++c) {
#pragma unroll
        for (int off = 32; off > 0; off >>= 1) {
            sum[c] += __shfl_down(sum[c], off);
            ssq[c] += __shfl_down(ssq[c], off);
        }
    }
    __shared__ float red[4][64];
    const int lane = threadIdx.x & 63, wave = threadIdx.x >> 6;
    if (lane == 0) {
#pragma unroll
        for (int c = 0; c < NCH; ++c) { red[wave][c] = sum[c]; red[wave][NCH+c] = ssq[c]; }
    }
    __syncthreads();
    if (threadIdx.x < 64)
        partials[(size_t)blockIdx.x * 64 + threadIdx.x] =
            red[0][threadIdx.x] + red[1][threadIdx.x] + red[2][threadIdx.x] + red[3][threadIdx.x];
}

__global__ __launch_bounds__(256) void k_finalize(
    const float* __restrict__ partials, int nblocks,
    const float* __restrict__ gamma, const float* __restrict__ beta,
    float* __restrict__ ab, float invE)
{
    __shared__ float acc[4][64];
    const int vtx = threadIdx.x & 63, chunk = threadIdx.x >> 6;
    float s = 0.f;
    for (int r = chunk; r < nblocks; r += 4) s += partials[(size_t)r * 64 + vtx];
    acc[chunk][vtx] = s;
    __syncthreads();
    if (threadIdx.x < 64) acc[0][vtx] = acc[0][vtx] + acc[1][vtx] + acc[2][vtx] + acc[3][vtx];
    __syncthreads();
    if (threadIdx.x < 32) {
        const int c = threadIdx.x;
        float mean = acc[0][c] * invE;
        float var  = acc[0][32 + c] * invE - mean * mean;
        float rstd = rsqrtf(var + 1e-5f);
        float a = gamma[c] * rstd;
        ab[c] = a; ab[32 + c] = beta[c] - mean * a;
    }
}

__global__ __launch_bounds__(256) void k_apply_atomic(
    const float* __restrict__ x,
    const int* __restrict__ srci, const int* __restrict__ tgti,
    const float* __restrict__ W, const float* __restrict__ ab,
    float* __restrict__ out, int E)
{
    const int e = blockIdx.x * 256 + threadIdx.x;
    if (e >= E) return;
    const int s = srci[e], t = tgti[e];
    const float4* ps = (const float4*)(x + (size_t)s * NCH);
    const float4* pt = (const float4*)(x + (size_t)t * NCH);
    float xs[NCH], dx[NCH];
#pragma unroll
    for (int i = 0; i < 8; ++i) {
        float4 a = ps[i], bb = pt[i];
        xs[4*i+0] = a.x; xs[4*i+1] = a.y; xs[4*i+2] = a.z; xs[4*i+3] = a.w;
        dx[4*i+0] = bb.x - a.x; dx[4*i+1] = bb.y - a.y;
        dx[4*i+2] = bb.z - a.z; dx[4*i+3] = bb.w - a.w;
    }
    float* orow = out + (size_t)s * NCH;
#pragma unroll
    for (int c = 0; c < NCH; ++c) {
        const float* wr = W + c * 64;
        float y = 0.f;
#pragma unroll
        for (int k = 0; k < NCH; ++k) y = fmaf(wr[k], xs[k], y);
#pragma unroll
        for (int k = 0; k < NCH; ++k) y = fmaf(wr[32 + k], dx[k], y);
        float z = fmaf(ab[c], y, ab[32 + c]);
        z = (z > 0.f) ? z : (__expf(z) - 1.0f);
        atomicAdd(orow + c, z);
    }
}

// ===========================================================================
extern "C" void kernel_launch(void* const* d_in, const int* in_sizes, int n_in,
                              void* d_out, int out_size, void* d_ws, size_t ws_size,
                              hipStream_t stream)
{
    const float* x     = (const float*)d_in[0];
    const int*   ei    = (const int*)d_in[1];
    const float* W     = (const float*)d_in[2];
    const float* gamma = (const float*)d_in[3];
    const float* beta  = (const float*)d_in[4];
    const int E = in_sizes[1] / 2;
    const int N = in_sizes[0] / NCH;
    const int* srci = ei;
    const int* tgti = ei + E;

    const int SB = 1024;           // stats grid
    const int AB = 2048;           // apply grid

    // ws layout: uh,vh (bf16) | uq,vq (fp8) | outh (bf16x2) | partials | ab | ticket
    ushort_t* uh      = (ushort_t*)d_ws;
    ushort_t* vh      = uh + (size_t)N * NCH;
    uchar_t*  uq      = (uchar_t*)(vh + (size_t)N * NCH);
    uchar_t*  vq      = uq + (size_t)N * NCH;
    __hip_bfloat162* outh = (__hip_bfloat162*)(vq + (size_t)N * NCH);
    float*    partials= (float*)((ushort_t*)outh + (size_t)N * NCH);
    float*    ab      = partials + (size_t)SB * 64;
    int*      ticket  = (int*)(ab + 64);
    const size_t need = (size_t)((char*)(ticket + 1) - (char*)d_ws);

    if (ws_size >= need) {
        k_uv3z<<<(N + 7) / 8, 256, 0, stream>>>(x, W, uh, vh, uq, vq,
                                                (uint_t*)outh, ticket, N);
        k_stats8f<<<SB, 256, 0, stream>>>(uq, vq, srci, tgti, partials, ticket,
                                          gamma, beta, ab, 1.0f / (float)E, E);
        k_apply_pk<<<AB, 256, 0, stream>>>(uh, vh, srci, tgti, ab, outh, E);
        k_cvt<<<(N * 16 + 255) / 256, 256, 0, stream>>>((const uint_t*)outh,
                                                        (float*)d_out, N * 16);
    } else {
        const int SBf = 512;
        float* abf      = (float*)d_ws;
        float* partialsf = abf + 64;
        hipMemsetAsync(d_out, 0, (size_t)out_size * sizeof(float), stream);
        k_stats_hist<<<SBf, 256, 0, stream>>>(x, srci, tgti, W, partialsf, E);
        k_finalize<<<1, 256, 0, stream>>>(partialsf, SBf, gamma, beta, abf, 1.0f / (float)E);
        k_apply_atomic<<<(E + 255) / 256, 256, 0, stream>>>(x, srci, tgti, W, abf,
                                                            (float*)d_out, E);
    }
}